// Round 6
// baseline (342.190 us; speedup 1.0000x reference)
//
#include <hip/hip_runtime.h>
#include <hip/hip_bf16.h>

#define HID 96
#define NGRAPHS 64
#define SENT 0xC3C3u   // 50115: sentinel row (zeroed) for CSR padding
#define NROWS 50116    // N + sentinel row

typedef __attribute__((ext_vector_type(8))) short short8;
typedef __attribute__((ext_vector_type(4))) float floatx4;
typedef __attribute__((ext_vector_type(8))) unsigned short ushort8v;

__device__ __forceinline__ float bf16_to_f32(unsigned short u) {
    unsigned int v = ((unsigned int)u) << 16;
    return __builtin_bit_cast(float, v);
}
__device__ __forceinline__ unsigned short f32_to_bf16(float f) {
    unsigned int u = __builtin_bit_cast(unsigned int, f);
    u += 0x7fff + ((u >> 16) & 1);  // RNE
    return (unsigned short)(u >> 16);
}

// ---------------------------------------------------------------- degree ----
__global__ void deg_kernel(const int* __restrict__ dst, int* __restrict__ deg,
                           int n_edges) {
    int t = blockIdx.x * blockDim.x + threadIdx.x;
    int e0 = t * 4;
    if (e0 + 4 <= n_edges) {
        int4 d4 = *(const int4*)(dst + e0);
        atomicAdd(&deg[d4.x], 1);
        atomicAdd(&deg[d4.y], 1);
        atomicAdd(&deg[d4.z], 1);
        atomicAdd(&deg[d4.w], 1);
    } else {
        for (int e = e0; e < n_edges; e++) atomicAdd(&deg[dst[e]], 1);
    }
}

// ------------------------------------------- scan (padded to 8) + dinv ------
__global__ __launch_bounds__(256) void scan_phaseA(const int* __restrict__ deg,
                                                   float* __restrict__ dinv,
                                                   int* __restrict__ blocksum,
                                                   int N) {
    int i = blockIdx.x * 256 + threadIdx.x;
    int d = (i < N) ? deg[i] : 0;
    if (i < N) dinv[i] = rsqrtf((float)d + 1.0f);
    int v = (d + 7) & ~7;  // padded degree
#pragma unroll
    for (int off = 32; off > 0; off >>= 1) v += __shfl_down(v, off, 64);
    __shared__ int s[4];
    if ((threadIdx.x & 63) == 0) s[threadIdx.x >> 6] = v;
    __syncthreads();
    if (threadIdx.x == 0) blocksum[blockIdx.x] = s[0] + s[1] + s[2] + s[3];
}

__global__ __launch_bounds__(256) void scan_phaseB(int* __restrict__ blocksum,
                                                   int* __restrict__ blockoff,
                                                   int nblocks) {
    __shared__ int s[256];
    int t = threadIdx.x;
    int own = (t < nblocks) ? blocksum[t] : 0;
    s[t] = own;
    __syncthreads();
#pragma unroll
    for (int off = 1; off < 256; off <<= 1) {
        int v = (t >= off) ? s[t - off] : 0;
        __syncthreads();
        s[t] += v;
        __syncthreads();
    }
    if (t < nblocks) blockoff[t] = s[t] - own;  // exclusive
}

__global__ __launch_bounds__(256) void scan_phaseC(const int* __restrict__ deg,
                                                   const int* __restrict__ blockoff,
                                                   int* __restrict__ rowptr,
                                                   int* __restrict__ cursor, int N) {
    __shared__ int s[256];
    int t = threadIdx.x;
    int i = blockIdx.x * 256 + t;
    int own = (i < N) ? (deg[i] + 7) & ~7 : 0;
    s[t] = own;
    __syncthreads();
#pragma unroll
    for (int off = 1; off < 256; off <<= 1) {
        int v = (t >= off) ? s[t - off] : 0;
        __syncthreads();
        s[t] += v;
        __syncthreads();
    }
    if (i < N) {
        int r = blockoff[blockIdx.x] + s[t] - own;
        rowptr[i] = r;
        cursor[i] = r;               // seed: atomics return absolute positions
        if (i == N - 1) rowptr[N] = r + own;
    }
}

// ------------------------------------------------------------------ fill ----
__global__ void csr_fill(const int* __restrict__ src, const int* __restrict__ dst,
                         int* __restrict__ cursor,
                         unsigned short* __restrict__ csr_src, int n_edges) {
    int t = blockIdx.x * blockDim.x + threadIdx.x;
    int e0 = t * 4;
    if (e0 + 4 <= n_edges) {
        int4 d4 = *(const int4*)(dst + e0);
        int4 s4 = *(const int4*)(src + e0);
        int p0 = atomicAdd(&cursor[d4.x], 1);
        int p1 = atomicAdd(&cursor[d4.y], 1);
        int p2 = atomicAdd(&cursor[d4.z], 1);
        int p3 = atomicAdd(&cursor[d4.w], 1);
        csr_src[p0] = (unsigned short)s4.x;
        csr_src[p1] = (unsigned short)s4.y;
        csr_src[p2] = (unsigned short)s4.z;
        csr_src[p3] = (unsigned short)s4.w;
    } else {
        for (int e = e0; e < n_edges; e++) {
            int p = atomicAdd(&cursor[dst[e]], 1);
            csr_src[p] = (unsigned short)src[e];
        }
    }
}

// ----------------------------------------------------------- weight prep ----
__global__ void swizzle_W(const float* __restrict__ W0, const float* __restrict__ W1,
                          const float* __restrict__ W2, unsigned short* __restrict__ Wz) {
    const float* W = (blockIdx.x == 0) ? W0 : (blockIdx.x == 1) ? W1 : W2;
    unsigned short* dst = Wz + blockIdx.x * HID * HID;
    for (int e = threadIdx.x; e < HID * HID; e += blockDim.x) {
        int k = e / HID, n = e % HID;
        int nt = n >> 4, kki = k >> 5, quad = (k >> 3) & 3, j = k & 7;
        int lane = (n & 15) | (quad << 4);
        dst[(((nt * 3 + kki) * 64 + lane) << 3) | j] = f32_to_bf16(W[e]);
    }
}

__global__ void zero_sentinel(unsigned short* __restrict__ a,
                              unsigned short* __restrict__ b) {
    int t = threadIdx.x;  // 96 threads
    a[(size_t)SENT * HID + t] = 0;
    b[(size_t)SENT * HID + t] = 0;
}

// ----------------------------------------------------- GEMM0 (f32 input) ----
// Out[m] = bf16( (x[m] @ W0) * dinv[m] )
__global__ __launch_bounds__(256) void gemm0_f32(
    const float* __restrict__ X, const unsigned short* __restrict__ Wz,
    const float* __restrict__ dinv, unsigned short* __restrict__ Out, int Mtiles) {
    int wave = threadIdx.x >> 6;
    int lane = threadIdx.x & 63;
    int quad = lane >> 4;
    int mrow = lane & 15;
    int tt = blockIdx.x * 4 + wave;
    if (tt >= Mtiles) return;

    short8 bfrag[18];
    const short8* Wz8 = (const short8*)Wz;
#pragma unroll
    for (int f = 0; f < 18; f++) bfrag[f] = Wz8[f * 64 + lane];

    int m0 = tt * 16;
    const float* arow = X + (size_t)(m0 + mrow) * HID + quad * 8;
    short8 a[3];
#pragma unroll
    for (int kb = 0; kb < 3; kb++) {
        float4 u = *(const float4*)(arow + kb * 32);
        float4 v = *(const float4*)(arow + kb * 32 + 4);
        short8 t;
        t[0] = (short)f32_to_bf16(u.x); t[1] = (short)f32_to_bf16(u.y);
        t[2] = (short)f32_to_bf16(u.z); t[3] = (short)f32_to_bf16(u.w);
        t[4] = (short)f32_to_bf16(v.x); t[5] = (short)f32_to_bf16(v.y);
        t[6] = (short)f32_to_bf16(v.z); t[7] = (short)f32_to_bf16(v.w);
        a[kb] = t;
    }
    float dscale[4];
#pragma unroll
    for (int r = 0; r < 4; r++) dscale[r] = dinv[m0 + quad * 4 + r];
    unsigned short* orow = Out + (size_t)m0 * HID;
#pragma unroll
    for (int nt = 0; nt < 6; nt++) {
        floatx4 c = {0.0f, 0.0f, 0.0f, 0.0f};
        c = __builtin_amdgcn_mfma_f32_16x16x32_bf16(a[0], bfrag[nt * 3 + 0], c, 0, 0, 0);
        c = __builtin_amdgcn_mfma_f32_16x16x32_bf16(a[1], bfrag[nt * 3 + 1], c, 0, 0, 0);
        c = __builtin_amdgcn_mfma_f32_16x16x32_bf16(a[2], bfrag[nt * 3 + 2], c, 0, 0, 0);
#pragma unroll
        for (int r = 0; r < 4; r++)
            orow[(size_t)(quad * 4 + r) * HID + nt * 16 + mrow] =
                f32_to_bf16(c[r] * dscale[r]);
    }
}

// ------------------------------------------------ fused gather + GEMM -------
// Per wave: gather 16 nodes of layer-l output (bias+ReLU) into a private LDS
// tile, then MFMA vs next layer's W. h is prescaled by dinv[src].
__global__ __launch_bounds__(256) void fused_gather_gemm(
    const unsigned short* __restrict__ h, const int* __restrict__ rowptr,
    const unsigned short* __restrict__ csr, const float* __restrict__ dinv,
    const float* __restrict__ bias, const unsigned short* __restrict__ Wz,
    unsigned short* __restrict__ Out, int Mtiles) {
    __shared__ unsigned short tile[4][16][104];  // stride 104: 2-way-free banks
    int wv = threadIdx.x >> 6;
    int lane = threadIdx.x & 63;
    int quad = lane >> 4;
    int mrow = lane & 15;
    int tt = blockIdx.x * 4 + wv;
    if (tt >= Mtiles) return;
    int fi = (lane < 48) ? lane * 2 : 94;
    float b0 = bias[fi], b1 = bias[fi + 1];

    short8 bfrag[18];
    const short8* Wz8 = (const short8*)Wz;
#pragma unroll
    for (int f = 0; f < 18; f++) bfrag[f] = Wz8[f * 64 + lane];

    int n0 = tt * 16;
    for (int j = 0; j < 16; j++) {
        int n = n0 + j;
        int i = rowptr[n];
        int end = rowptr[n + 1];  // 8-aligned; pads hit zeroed sentinel row
        float di = dinv[n];
        ushort2 hv = *(const ushort2*)(h + (size_t)n * HID + fi);
        float a0 = bf16_to_f32(hv.x);
        float a1 = bf16_to_f32(hv.y);
        for (; i < end; i += 8) {
            ushort8v iv = *(const ushort8v*)(csr + i);
            ushort2 v0 = *(const ushort2*)(h + (size_t)iv[0] * HID + fi);
            ushort2 v1 = *(const ushort2*)(h + (size_t)iv[1] * HID + fi);
            ushort2 v2 = *(const ushort2*)(h + (size_t)iv[2] * HID + fi);
            ushort2 v3 = *(const ushort2*)(h + (size_t)iv[3] * HID + fi);
            ushort2 v4 = *(const ushort2*)(h + (size_t)iv[4] * HID + fi);
            ushort2 v5 = *(const ushort2*)(h + (size_t)iv[5] * HID + fi);
            ushort2 v6 = *(const ushort2*)(h + (size_t)iv[6] * HID + fi);
            ushort2 v7 = *(const ushort2*)(h + (size_t)iv[7] * HID + fi);
            a0 += bf16_to_f32(v0.x) + bf16_to_f32(v1.x) + bf16_to_f32(v2.x) +
                  bf16_to_f32(v3.x) + bf16_to_f32(v4.x) + bf16_to_f32(v5.x) +
                  bf16_to_f32(v6.x) + bf16_to_f32(v7.x);
            a1 += bf16_to_f32(v0.y) + bf16_to_f32(v1.y) + bf16_to_f32(v2.y) +
                  bf16_to_f32(v3.y) + bf16_to_f32(v4.y) + bf16_to_f32(v5.y) +
                  bf16_to_f32(v6.y) + bf16_to_f32(v7.y);
        }
        a0 = fmaxf(a0 * di + b0, 0.0f);
        a1 = fmaxf(a1 * di + b1, 0.0f);
        if (lane < 48) {
            tile[wv][j][fi] = f32_to_bf16(a0);
            tile[wv][j][fi + 1] = f32_to_bf16(a1);
        }
    }
    // wave-private tile: no __syncthreads needed (compiler orders LDS deps)
    const unsigned short* tp = &tile[wv][0][0];
    short8 a[3];
#pragma unroll
    for (int kb = 0; kb < 3; kb++)
        a[kb] = *(const short8*)(tp + mrow * 104 + quad * 8 + kb * 32);
    float dscale[4];
#pragma unroll
    for (int r = 0; r < 4; r++) dscale[r] = dinv[n0 + quad * 4 + r];
    unsigned short* orow = Out + (size_t)n0 * HID;
#pragma unroll
    for (int nt = 0; nt < 6; nt++) {
        floatx4 c = {0.0f, 0.0f, 0.0f, 0.0f};
        c = __builtin_amdgcn_mfma_f32_16x16x32_bf16(a[0], bfrag[nt * 3 + 0], c, 0, 0, 0);
        c = __builtin_amdgcn_mfma_f32_16x16x32_bf16(a[1], bfrag[nt * 3 + 1], c, 0, 0, 0);
        c = __builtin_amdgcn_mfma_f32_16x16x32_bf16(a[2], bfrag[nt * 3 + 2], c, 0, 0, 0);
#pragma unroll
        for (int r = 0; r < 4; r++)
            orow[(size_t)(quad * 4 + r) * HID + nt * 16 + mrow] =
                f32_to_bf16(c[r] * dscale[r]);
    }
}

// ------------------------------------------------- fused gather + pool ------
// Last layer: never materialize activations; run-length accumulate into psum.
__global__ __launch_bounds__(256) void gather_pool(
    const unsigned short* __restrict__ h, const int* __restrict__ rowptr,
    const unsigned short* __restrict__ csr, const float* __restrict__ dinv,
    const float* __restrict__ bias, const int* __restrict__ batch,
    float* __restrict__ psum, float* __restrict__ pcnt, int Mtiles) {
    int wv = threadIdx.x >> 6;
    int lane = threadIdx.x & 63;
    int tt = blockIdx.x * 4 + wv;
    if (tt >= Mtiles) return;
    int fi = (lane < 48) ? lane * 2 : 94;
    float b0 = bias[fi], b1 = bias[fi + 1];

    int n0 = tt * 16;
    int g_cur = batch[n0];
    float s0 = 0.0f, s1 = 0.0f;
    int cnt = 0;
    for (int j = 0; j < 16; j++) {
        int n = n0 + j;
        int i = rowptr[n];
        int end = rowptr[n + 1];
        float di = dinv[n];
        ushort2 hv = *(const ushort2*)(h + (size_t)n * HID + fi);
        float a0 = bf16_to_f32(hv.x);
        float a1 = bf16_to_f32(hv.y);
        for (; i < end; i += 8) {
            ushort8v iv = *(const ushort8v*)(csr + i);
            ushort2 v0 = *(const ushort2*)(h + (size_t)iv[0] * HID + fi);
            ushort2 v1 = *(const ushort2*)(h + (size_t)iv[1] * HID + fi);
            ushort2 v2 = *(const ushort2*)(h + (size_t)iv[2] * HID + fi);
            ushort2 v3 = *(const ushort2*)(h + (size_t)iv[3] * HID + fi);
            ushort2 v4 = *(const ushort2*)(h + (size_t)iv[4] * HID + fi);
            ushort2 v5 = *(const ushort2*)(h + (size_t)iv[5] * HID + fi);
            ushort2 v6 = *(const ushort2*)(h + (size_t)iv[6] * HID + fi);
            ushort2 v7 = *(const ushort2*)(h + (size_t)iv[7] * HID + fi);
            a0 += bf16_to_f32(v0.x) + bf16_to_f32(v1.x) + bf16_to_f32(v2.x) +
                  bf16_to_f32(v3.x) + bf16_to_f32(v4.x) + bf16_to_f32(v5.x) +
                  bf16_to_f32(v6.x) + bf16_to_f32(v7.x);
            a1 += bf16_to_f32(v0.y) + bf16_to_f32(v1.y) + bf16_to_f32(v2.y) +
                  bf16_to_f32(v3.y) + bf16_to_f32(v4.y) + bf16_to_f32(v5.y) +
                  bf16_to_f32(v6.y) + bf16_to_f32(v7.y);
        }
        a0 = a0 * di + b0;  // last layer: no ReLU
        a1 = a1 * di + b1;
        int g = batch[n];
        if (g != g_cur) {
            if (lane < 48) {
                atomicAdd(&psum[g_cur * HID + fi], s0);
                atomicAdd(&psum[g_cur * HID + fi + 1], s1);
            }
            if (lane == 0) atomicAdd(&pcnt[g_cur], (float)cnt);
            s0 = 0.0f; s1 = 0.0f; cnt = 0;
            g_cur = g;
        }
        s0 += a0;
        s1 += a1;
        cnt++;
    }
    if (lane < 48) {
        atomicAdd(&psum[g_cur * HID + fi], s0);
        atomicAdd(&psum[g_cur * HID + fi + 1], s1);
    }
    if (lane == 0) atomicAdd(&pcnt[g_cur], (float)cnt);
}

// ---------------------------------------------------------------- head ------
__global__ __launch_bounds__(640) void final_kernel(
    const float* __restrict__ sums, const float* __restrict__ cnts,
    const float* __restrict__ Wlin, const float* __restrict__ blin,
    float* __restrict__ out) {
    int t = threadIdx.x;
    if (t >= NGRAPHS * 10) return;
    int g = t / 10;
    int c = t % 10;
    float denom = fmaxf(cnts[g], 1.0f);
    float acc = blin[c];
#pragma unroll
    for (int f = 0; f < HID; f++)
        acc += (sums[g * HID + f] / denom) * Wlin[f * 10 + c];
    out[t] = acc;
}

// ---------------------------------------------------------------- launch ----
extern "C" void kernel_launch(void* const* d_in, const int* in_sizes, int n_in,
                              void* d_out, int out_size, void* d_ws,
                              size_t ws_size, hipStream_t stream) {
    const float* x = (const float*)d_in[0];
    const int* edge = (const int*)d_in[1];
    const int* batch = (const int*)d_in[2];
    const float* W[3] = {(const float*)d_in[3], (const float*)d_in[5],
                         (const float*)d_in[7]};
    const float* B[3] = {(const float*)d_in[4], (const float*)d_in[6],
                         (const float*)d_in[8]};
    const float* Wlin = (const float*)d_in[9];
    const float* blin = (const float*)d_in[10];
    float* out = (float*)d_out;

    int N = in_sizes[0] / HID;  // 50000
    int E = in_sizes[1] / 2;    // 800000
    const int* src = edge;
    const int* dst = edge + E;
    int NB = (N + 255) / 256;

    char* ws = (char*)d_ws;
    size_t off = 0;
    auto alloc = [&](size_t bytes) {
        void* p = ws + off;
        off += (bytes + 255) & ~(size_t)255;
        return p;
    };
    int* deg = (int*)alloc((size_t)N * 4);
    float* dinv = (float*)alloc((size_t)N * 4);
    int* rowptr = (int*)alloc(((size_t)N + 1) * 4);
    int* cursor = (int*)alloc((size_t)N * 4);
    int* blocksum = (int*)alloc((size_t)NB * 4);
    int* blockoff = (int*)alloc((size_t)NB * 4);
    size_t csr_cap = (size_t)E + 8 * (size_t)N;
    unsigned short* csr_src = (unsigned short*)alloc(csr_cap * 2);
    unsigned short* Wz = (unsigned short*)alloc(3 * HID * HID * 2);
    unsigned short* bufA = (unsigned short*)alloc((size_t)NROWS * HID * 2);
    unsigned short* bufB = (unsigned short*)alloc((size_t)NROWS * HID * 2);
    float* psum = (float*)alloc((NGRAPHS * HID + NGRAPHS) * 4);
    float* pcnt = psum + NGRAPHS * HID;

    // --- CSR build + weight prep ---
    hipMemsetAsync(deg, 0, (size_t)N * 4, stream);
    hipMemsetAsync(csr_src, 0xC3, csr_cap * 2, stream);  // pads -> sentinel row
    hipMemsetAsync(psum, 0, (NGRAPHS * HID + NGRAPHS) * 4, stream);
    deg_kernel<<<(E / 4 + 255) / 256, 256, 0, stream>>>(dst, deg, E);
    scan_phaseA<<<NB, 256, 0, stream>>>(deg, dinv, blocksum, N);
    scan_phaseB<<<1, 256, 0, stream>>>(blocksum, blockoff, NB);
    scan_phaseC<<<NB, 256, 0, stream>>>(deg, blockoff, rowptr, cursor, N);
    csr_fill<<<(E / 4 + 255) / 256, 256, 0, stream>>>(src, dst, cursor, csr_src, E);
    swizzle_W<<<3, 256, 0, stream>>>(W[0], W[1], W[2], Wz);
    zero_sentinel<<<1, HID, 0, stream>>>(bufA, bufB);

    int Mtiles = (N + 15) / 16;          // 3125 (N divisible by 16)
    int grid16 = (Mtiles + 3) / 4;       // 782 blocks of 4 waves

    gemm0_f32<<<grid16, 256, 0, stream>>>(x, Wz, dinv, bufA, Mtiles);
    fused_gather_gemm<<<grid16, 256, 0, stream>>>(
        bufA, rowptr, csr_src, dinv, B[0], Wz + 1 * HID * HID, bufB, Mtiles);
    fused_gather_gemm<<<grid16, 256, 0, stream>>>(
        bufB, rowptr, csr_src, dinv, B[1], Wz + 2 * HID * HID, bufA, Mtiles);
    gather_pool<<<grid16, 256, 0, stream>>>(bufA, rowptr, csr_src, dinv, B[2],
                                            batch, psum, pcnt, Mtiles);
    final_kernel<<<1, 640, 0, stream>>>(psum, pcnt, Wlin, blin, out);
}

// Round 7
// 324.041 us; speedup vs baseline: 1.0560x; 1.0560x over previous
//
#include <hip/hip_runtime.h>
#include <hip/hip_bf16.h>

#define HID 96
#define NGRAPHS 64
#define SENT 0xC3C3u   // 50115: sentinel row (zeroed) for CSR padding
#define NROWS 50116    // N + sentinel row

typedef __attribute__((ext_vector_type(8))) short short8;
typedef __attribute__((ext_vector_type(4))) float floatx4;
typedef __attribute__((ext_vector_type(8))) unsigned short ushort8v;

__device__ __forceinline__ float bf16_to_f32(unsigned short u) {
    unsigned int v = ((unsigned int)u) << 16;
    return __builtin_bit_cast(float, v);
}
__device__ __forceinline__ unsigned short f32_to_bf16(float f) {
    unsigned int u = __builtin_bit_cast(unsigned int, f);
    u += 0x7fff + ((u >> 16) & 1);  // RNE
    return (unsigned short)(u >> 16);
}

// Gather one CSR row range into (a0,a1); 8 edges per iteration, 9 outstanding loads.
__device__ __forceinline__ void gather_row(const unsigned short* __restrict__ h,
                                           const unsigned short* __restrict__ csr,
                                           int i, int end, int fi, float& a0,
                                           float& a1) {
    for (; i < end; i += 8) {
        ushort8v iv = *(const ushort8v*)(csr + i);
        ushort2 v0 = *(const ushort2*)(h + (size_t)iv[0] * HID + fi);
        ushort2 v1 = *(const ushort2*)(h + (size_t)iv[1] * HID + fi);
        ushort2 v2 = *(const ushort2*)(h + (size_t)iv[2] * HID + fi);
        ushort2 v3 = *(const ushort2*)(h + (size_t)iv[3] * HID + fi);
        ushort2 v4 = *(const ushort2*)(h + (size_t)iv[4] * HID + fi);
        ushort2 v5 = *(const ushort2*)(h + (size_t)iv[5] * HID + fi);
        ushort2 v6 = *(const ushort2*)(h + (size_t)iv[6] * HID + fi);
        ushort2 v7 = *(const ushort2*)(h + (size_t)iv[7] * HID + fi);
        a0 += bf16_to_f32(v0.x) + bf16_to_f32(v1.x) + bf16_to_f32(v2.x) +
              bf16_to_f32(v3.x) + bf16_to_f32(v4.x) + bf16_to_f32(v5.x) +
              bf16_to_f32(v6.x) + bf16_to_f32(v7.x);
        a1 += bf16_to_f32(v0.y) + bf16_to_f32(v1.y) + bf16_to_f32(v2.y) +
              bf16_to_f32(v3.y) + bf16_to_f32(v4.y) + bf16_to_f32(v5.y) +
              bf16_to_f32(v6.y) + bf16_to_f32(v7.y);
    }
}

// ---------------------------------------------------------------- degree ----
__global__ void deg_kernel(const int* __restrict__ dst, int* __restrict__ deg,
                           int n_edges) {
    int t = blockIdx.x * blockDim.x + threadIdx.x;
    int e0 = t * 4;
    if (e0 + 4 <= n_edges) {
        int4 d4 = *(const int4*)(dst + e0);
        atomicAdd(&deg[d4.x], 1);
        atomicAdd(&deg[d4.y], 1);
        atomicAdd(&deg[d4.z], 1);
        atomicAdd(&deg[d4.w], 1);
    } else {
        for (int e = e0; e < n_edges; e++) atomicAdd(&deg[dst[e]], 1);
    }
}

// ------------------------------------------- scan (padded to 8) + dinv ------
__global__ __launch_bounds__(256) void scan_phaseA(const int* __restrict__ deg,
                                                   float* __restrict__ dinv,
                                                   int* __restrict__ blocksum,
                                                   int N) {
    int i = blockIdx.x * 256 + threadIdx.x;
    int d = (i < N) ? deg[i] : 0;
    if (i < N) dinv[i] = rsqrtf((float)d + 1.0f);
    int v = (d + 7) & ~7;  // padded degree
#pragma unroll
    for (int off = 32; off > 0; off >>= 1) v += __shfl_down(v, off, 64);
    __shared__ int s[4];
    if ((threadIdx.x & 63) == 0) s[threadIdx.x >> 6] = v;
    __syncthreads();
    if (threadIdx.x == 0) blocksum[blockIdx.x] = s[0] + s[1] + s[2] + s[3];
}

__global__ __launch_bounds__(256) void scan_phaseB(int* __restrict__ blocksum,
                                                   int* __restrict__ blockoff,
                                                   int nblocks) {
    __shared__ int s[256];
    int t = threadIdx.x;
    int own = (t < nblocks) ? blocksum[t] : 0;
    s[t] = own;
    __syncthreads();
#pragma unroll
    for (int off = 1; off < 256; off <<= 1) {
        int v = (t >= off) ? s[t - off] : 0;
        __syncthreads();
        s[t] += v;
        __syncthreads();
    }
    if (t < nblocks) blockoff[t] = s[t] - own;  // exclusive
}

__global__ __launch_bounds__(256) void scan_phaseC(const int* __restrict__ deg,
                                                   const int* __restrict__ blockoff,
                                                   int* __restrict__ rowptr,
                                                   int* __restrict__ cursor, int N) {
    __shared__ int s[256];
    int t = threadIdx.x;
    int i = blockIdx.x * 256 + t;
    int own = (i < N) ? (deg[i] + 7) & ~7 : 0;
    s[t] = own;
    __syncthreads();
#pragma unroll
    for (int off = 1; off < 256; off <<= 1) {
        int v = (t >= off) ? s[t - off] : 0;
        __syncthreads();
        s[t] += v;
        __syncthreads();
    }
    if (i < N) {
        int r = blockoff[blockIdx.x] + s[t] - own;
        rowptr[i] = r;
        cursor[i] = r;               // seed: atomics return absolute positions
        if (i == N - 1) rowptr[N] = r + own;
    }
}

// ------------------------------------------------------------------ fill ----
__global__ void csr_fill(const int* __restrict__ src, const int* __restrict__ dst,
                         int* __restrict__ cursor,
                         unsigned short* __restrict__ csr_src, int n_edges) {
    int t = blockIdx.x * blockDim.x + threadIdx.x;
    int e0 = t * 4;
    if (e0 + 4 <= n_edges) {
        int4 d4 = *(const int4*)(dst + e0);
        int4 s4 = *(const int4*)(src + e0);
        int p0 = atomicAdd(&cursor[d4.x], 1);
        int p1 = atomicAdd(&cursor[d4.y], 1);
        int p2 = atomicAdd(&cursor[d4.z], 1);
        int p3 = atomicAdd(&cursor[d4.w], 1);
        csr_src[p0] = (unsigned short)s4.x;
        csr_src[p1] = (unsigned short)s4.y;
        csr_src[p2] = (unsigned short)s4.z;
        csr_src[p3] = (unsigned short)s4.w;
    } else {
        for (int e = e0; e < n_edges; e++) {
            int p = atomicAdd(&cursor[dst[e]], 1);
            csr_src[p] = (unsigned short)src[e];
        }
    }
}

// ----------------------------------------------------------- weight prep ----
__global__ void swizzle_W(const float* __restrict__ W0, const float* __restrict__ W1,
                          const float* __restrict__ W2, unsigned short* __restrict__ Wz) {
    const float* W = (blockIdx.x == 0) ? W0 : (blockIdx.x == 1) ? W1 : W2;
    unsigned short* dst = Wz + blockIdx.x * HID * HID;
    for (int e = threadIdx.x; e < HID * HID; e += blockDim.x) {
        int k = e / HID, n = e % HID;
        int nt = n >> 4, kki = k >> 5, quad = (k >> 3) & 3, j = k & 7;
        int lane = (n & 15) | (quad << 4);
        dst[(((nt * 3 + kki) * 64 + lane) << 3) | j] = f32_to_bf16(W[e]);
    }
}

__global__ void zero_sentinel(unsigned short* __restrict__ a,
                              unsigned short* __restrict__ b) {
    int t = threadIdx.x;  // 96 threads
    a[(size_t)SENT * HID + t] = 0;
    b[(size_t)SENT * HID + t] = 0;
}

// ----------------------------------------------------- GEMM0 (f32 input) ----
// 2 waves per 16-row tile; each wave computes 3 of the 6 n-tiles.
__global__ __launch_bounds__(256) void gemm0_f32(
    const float* __restrict__ X, const unsigned short* __restrict__ Wz,
    const float* __restrict__ dinv, unsigned short* __restrict__ Out, int Mtiles) {
    int wv = threadIdx.x >> 6;
    int lane = threadIdx.x & 63;
    int quad = lane >> 4;
    int mrow = lane & 15;
    int tt = blockIdx.x * 2 + (wv >> 1);
    int half = wv & 1;
    if (tt >= Mtiles) return;

    short8 bfrag[9];
    const short8* Wz8 = (const short8*)Wz;
#pragma unroll
    for (int f = 0; f < 9; f++) bfrag[f] = Wz8[(half * 9 + f) * 64 + lane];

    int m0 = tt * 16;
    const float* arow = X + (size_t)(m0 + mrow) * HID + quad * 8;
    short8 a[3];
#pragma unroll
    for (int kb = 0; kb < 3; kb++) {
        float4 u = *(const float4*)(arow + kb * 32);
        float4 v = *(const float4*)(arow + kb * 32 + 4);
        short8 t;
        t[0] = (short)f32_to_bf16(u.x); t[1] = (short)f32_to_bf16(u.y);
        t[2] = (short)f32_to_bf16(u.z); t[3] = (short)f32_to_bf16(u.w);
        t[4] = (short)f32_to_bf16(v.x); t[5] = (short)f32_to_bf16(v.y);
        t[6] = (short)f32_to_bf16(v.z); t[7] = (short)f32_to_bf16(v.w);
        a[kb] = t;
    }
    float dscale[4];
#pragma unroll
    for (int r = 0; r < 4; r++) dscale[r] = dinv[m0 + quad * 4 + r];
    unsigned short* orow = Out + (size_t)m0 * HID;
#pragma unroll
    for (int ntl = 0; ntl < 3; ntl++) {
        int nt = half * 3 + ntl;
        floatx4 c = {0.0f, 0.0f, 0.0f, 0.0f};
        c = __builtin_amdgcn_mfma_f32_16x16x32_bf16(a[0], bfrag[ntl * 3 + 0], c, 0, 0, 0);
        c = __builtin_amdgcn_mfma_f32_16x16x32_bf16(a[1], bfrag[ntl * 3 + 1], c, 0, 0, 0);
        c = __builtin_amdgcn_mfma_f32_16x16x32_bf16(a[2], bfrag[ntl * 3 + 2], c, 0, 0, 0);
#pragma unroll
        for (int r = 0; r < 4; r++)
            orow[(size_t)(quad * 4 + r) * HID + nt * 16 + mrow] =
                f32_to_bf16(c[r] * dscale[r]);
    }
}

// ------------------------------------------------ fused gather + GEMM -------
// 2 waves per 16-row tile: each gathers 8 rows into the shared LDS tile,
// barrier, then each MFMAs the full tile against 3 of the 6 n-tiles.
__global__ __launch_bounds__(256) void fused_gather_gemm(
    const unsigned short* __restrict__ h, const int* __restrict__ rowptr,
    const unsigned short* __restrict__ csr, const float* __restrict__ dinv,
    const float* __restrict__ bias, const unsigned short* __restrict__ Wz,
    unsigned short* __restrict__ Out, int Mtiles) {
    __shared__ unsigned short tile[2][16][104];  // stride 104
    int wv = threadIdx.x >> 6;
    int lane = threadIdx.x & 63;
    int quad = lane >> 4;
    int mrow = lane & 15;
    int tsel = wv >> 1;
    int half = wv & 1;
    int tt = blockIdx.x * 2 + tsel;
    bool active = tt < Mtiles;
    int fi = (lane < 48) ? lane * 2 : 94;

    if (active) {
        float b0 = bias[fi], b1 = bias[fi + 1];
        int n0 = tt * 16;
        for (int j = half * 8; j < half * 8 + 8; j++) {
            int n = n0 + j;
            int i = rowptr[n];
            int end = rowptr[n + 1];  // 8-aligned; pads hit zeroed sentinel
            float di = dinv[n];
            ushort2 hv = *(const ushort2*)(h + (size_t)n * HID + fi);
            float a0 = bf16_to_f32(hv.x);
            float a1 = bf16_to_f32(hv.y);
            gather_row(h, csr, i, end, fi, a0, a1);
            a0 = fmaxf(a0 * di + b0, 0.0f);
            a1 = fmaxf(a1 * di + b1, 0.0f);
            if (lane < 48) {
                tile[tsel][j][fi] = f32_to_bf16(a0);
                tile[tsel][j][fi + 1] = f32_to_bf16(a1);
            }
        }
    }
    __syncthreads();
    if (!active) return;

    short8 bfrag[9];
    const short8* Wz8 = (const short8*)Wz;
#pragma unroll
    for (int f = 0; f < 9; f++) bfrag[f] = Wz8[(half * 9 + f) * 64 + lane];

    const unsigned short* tp = &tile[tsel][0][0];
    short8 a[3];
#pragma unroll
    for (int kb = 0; kb < 3; kb++)
        a[kb] = *(const short8*)(tp + mrow * 104 + quad * 8 + kb * 32);
    int n0 = tt * 16;
    float dscale[4];
#pragma unroll
    for (int r = 0; r < 4; r++) dscale[r] = dinv[n0 + quad * 4 + r];
    unsigned short* orow = Out + (size_t)n0 * HID;
#pragma unroll
    for (int ntl = 0; ntl < 3; ntl++) {
        int nt = half * 3 + ntl;
        floatx4 c = {0.0f, 0.0f, 0.0f, 0.0f};
        c = __builtin_amdgcn_mfma_f32_16x16x32_bf16(a[0], bfrag[ntl * 3 + 0], c, 0, 0, 0);
        c = __builtin_amdgcn_mfma_f32_16x16x32_bf16(a[1], bfrag[ntl * 3 + 1], c, 0, 0, 0);
        c = __builtin_amdgcn_mfma_f32_16x16x32_bf16(a[2], bfrag[ntl * 3 + 2], c, 0, 0, 0);
#pragma unroll
        for (int r = 0; r < 4; r++)
            orow[(size_t)(quad * 4 + r) * HID + nt * 16 + mrow] =
                f32_to_bf16(c[r] * dscale[r]);
    }
}

// ------------------------------------------------- fused gather + pool ------
// Wave per 8 nodes; run-length accumulate into psum.
__global__ __launch_bounds__(256) void gather_pool(
    const unsigned short* __restrict__ h, const int* __restrict__ rowptr,
    const unsigned short* __restrict__ csr, const float* __restrict__ dinv,
    const float* __restrict__ bias, const int* __restrict__ batch,
    float* __restrict__ psum, float* __restrict__ pcnt, int Ntiles8) {
    int wv = threadIdx.x >> 6;
    int lane = threadIdx.x & 63;
    int tt = blockIdx.x * 4 + wv;
    if (tt >= Ntiles8) return;
    int fi = (lane < 48) ? lane * 2 : 94;
    float b0 = bias[fi], b1 = bias[fi + 1];

    int n0 = tt * 8;
    int g_cur = batch[n0];
    float s0 = 0.0f, s1 = 0.0f;
    int cnt = 0;
    for (int j = 0; j < 8; j++) {
        int n = n0 + j;
        int i = rowptr[n];
        int end = rowptr[n + 1];
        float di = dinv[n];
        ushort2 hv = *(const ushort2*)(h + (size_t)n * HID + fi);
        float a0 = bf16_to_f32(hv.x);
        float a1 = bf16_to_f32(hv.y);
        gather_row(h, csr, i, end, fi, a0, a1);
        a0 = a0 * di + b0;  // last layer: no ReLU
        a1 = a1 * di + b1;
        int g = batch[n];
        if (g != g_cur) {
            if (lane < 48) {
                atomicAdd(&psum[g_cur * HID + fi], s0);
                atomicAdd(&psum[g_cur * HID + fi + 1], s1);
            }
            if (lane == 0) atomicAdd(&pcnt[g_cur], (float)cnt);
            s0 = 0.0f; s1 = 0.0f; cnt = 0;
            g_cur = g;
        }
        s0 += a0;
        s1 += a1;
        cnt++;
    }
    if (lane < 48) {
        atomicAdd(&psum[g_cur * HID + fi], s0);
        atomicAdd(&psum[g_cur * HID + fi + 1], s1);
    }
    if (lane == 0) atomicAdd(&pcnt[g_cur], (float)cnt);
}

// ---------------------------------------------------------------- head ------
__global__ __launch_bounds__(640) void final_kernel(
    const float* __restrict__ sums, const float* __restrict__ cnts,
    const float* __restrict__ Wlin, const float* __restrict__ blin,
    float* __restrict__ out) {
    int t = threadIdx.x;
    if (t >= NGRAPHS * 10) return;
    int g = t / 10;
    int c = t % 10;
    float denom = fmaxf(cnts[g], 1.0f);
    float acc = blin[c];
#pragma unroll
    for (int f = 0; f < HID; f++)
        acc += (sums[g * HID + f] / denom) * Wlin[f * 10 + c];
    out[t] = acc;
}

// ---------------------------------------------------------------- launch ----
extern "C" void kernel_launch(void* const* d_in, const int* in_sizes, int n_in,
                              void* d_out, int out_size, void* d_ws,
                              size_t ws_size, hipStream_t stream) {
    const float* x = (const float*)d_in[0];
    const int* edge = (const int*)d_in[1];
    const int* batch = (const int*)d_in[2];
    const float* W[3] = {(const float*)d_in[3], (const float*)d_in[5],
                         (const float*)d_in[7]};
    const float* B[3] = {(const float*)d_in[4], (const float*)d_in[6],
                         (const float*)d_in[8]};
    const float* Wlin = (const float*)d_in[9];
    const float* blin = (const float*)d_in[10];
    float* out = (float*)d_out;

    int N = in_sizes[0] / HID;  // 50000
    int E = in_sizes[1] / 2;    // 800000
    const int* src = edge;
    const int* dst = edge + E;
    int NB = (N + 255) / 256;

    char* ws = (char*)d_ws;
    size_t off = 0;
    auto alloc = [&](size_t bytes) {
        void* p = ws + off;
        off += (bytes + 255) & ~(size_t)255;
        return p;
    };
    int* deg = (int*)alloc((size_t)N * 4);
    float* dinv = (float*)alloc((size_t)N * 4);
    int* rowptr = (int*)alloc(((size_t)N + 1) * 4);
    int* cursor = (int*)alloc((size_t)N * 4);
    int* blocksum = (int*)alloc((size_t)NB * 4);
    int* blockoff = (int*)alloc((size_t)NB * 4);
    size_t csr_cap = (size_t)E + 8 * (size_t)N;
    unsigned short* csr_src = (unsigned short*)alloc(csr_cap * 2);
    unsigned short* Wz = (unsigned short*)alloc(3 * HID * HID * 2);
    unsigned short* bufA = (unsigned short*)alloc((size_t)NROWS * HID * 2);
    unsigned short* bufB = (unsigned short*)alloc((size_t)NROWS * HID * 2);
    float* psum = (float*)alloc((NGRAPHS * HID + NGRAPHS) * 4);
    float* pcnt = psum + NGRAPHS * HID;

    // --- CSR build + weight prep ---
    hipMemsetAsync(deg, 0, (size_t)N * 4, stream);
    hipMemsetAsync(csr_src, 0xC3, csr_cap * 2, stream);  // pads -> sentinel row
    hipMemsetAsync(psum, 0, (NGRAPHS * HID + NGRAPHS) * 4, stream);
    deg_kernel<<<(E / 4 + 255) / 256, 256, 0, stream>>>(dst, deg, E);
    scan_phaseA<<<NB, 256, 0, stream>>>(deg, dinv, blocksum, N);
    scan_phaseB<<<1, 256, 0, stream>>>(blocksum, blockoff, NB);
    scan_phaseC<<<NB, 256, 0, stream>>>(deg, blockoff, rowptr, cursor, N);
    csr_fill<<<(E / 4 + 255) / 256, 256, 0, stream>>>(src, dst, cursor, csr_src, E);
    swizzle_W<<<3, 256, 0, stream>>>(W[0], W[1], W[2], Wz);
    zero_sentinel<<<1, HID, 0, stream>>>(bufA, bufB);

    int Mtiles = (N + 15) / 16;           // 3125
    int grid2 = (Mtiles + 1) / 2;         // 1563 blocks (2 tiles/block)
    int Ntiles8 = (N + 7) / 8;            // 6250
    int gridp = (Ntiles8 + 3) / 4;        // 1563 blocks

    gemm0_f32<<<grid2, 256, 0, stream>>>(x, Wz, dinv, bufA, Mtiles);
    fused_gather_gemm<<<grid2, 256, 0, stream>>>(
        bufA, rowptr, csr_src, dinv, B[0], Wz + 1 * HID * HID, bufB, Mtiles);
    fused_gather_gemm<<<grid2, 256, 0, stream>>>(
        bufB, rowptr, csr_src, dinv, B[1], Wz + 2 * HID * HID, bufA, Mtiles);
    gather_pool<<<gridp, 256, 0, stream>>>(bufA, rowptr, csr_src, dinv, B[2],
                                           batch, psum, pcnt, Ntiles8);
    final_kernel<<<1, 640, 0, stream>>>(psum, pcnt, Wlin, blin, out);
}

// Round 8
// 316.410 us; speedup vs baseline: 1.0815x; 1.0241x over previous
//
#include <hip/hip_runtime.h>
#include <hip/hip_bf16.h>

#define HID 96
#define NGRAPHS 64
#define SENT 0xC3C3u   // 50115: sentinel row (zeroed) for CSR padding
#define NROWS 50116    // N + sentinel row

typedef __attribute__((ext_vector_type(8))) short short8;
typedef __attribute__((ext_vector_type(4))) float floatx4;
typedef __attribute__((ext_vector_type(8))) unsigned short ushort8v;

__device__ __forceinline__ float bf16_to_f32(unsigned short u) {
    unsigned int v = ((unsigned int)u) << 16;
    return __builtin_bit_cast(float, v);
}
__device__ __forceinline__ unsigned short f32_to_bf16(float f) {
    unsigned int u = __builtin_bit_cast(unsigned int, f);
    u += 0x7fff + ((u >> 16) & 1);  // RNE
    return (unsigned short)(u >> 16);
}

// One 8-edge batch of one row.
__device__ __forceinline__ void gather_batch(const unsigned short* __restrict__ h,
                                             const unsigned short* __restrict__ csr,
                                             int i, int fi, float& a0, float& a1) {
    ushort8v iv = *(const ushort8v*)(csr + i);
    ushort2 v0 = *(const ushort2*)(h + (size_t)iv[0] * HID + fi);
    ushort2 v1 = *(const ushort2*)(h + (size_t)iv[1] * HID + fi);
    ushort2 v2 = *(const ushort2*)(h + (size_t)iv[2] * HID + fi);
    ushort2 v3 = *(const ushort2*)(h + (size_t)iv[3] * HID + fi);
    ushort2 v4 = *(const ushort2*)(h + (size_t)iv[4] * HID + fi);
    ushort2 v5 = *(const ushort2*)(h + (size_t)iv[5] * HID + fi);
    ushort2 v6 = *(const ushort2*)(h + (size_t)iv[6] * HID + fi);
    ushort2 v7 = *(const ushort2*)(h + (size_t)iv[7] * HID + fi);
    a0 += bf16_to_f32(v0.x) + bf16_to_f32(v1.x) + bf16_to_f32(v2.x) +
          bf16_to_f32(v3.x) + bf16_to_f32(v4.x) + bf16_to_f32(v5.x) +
          bf16_to_f32(v6.x) + bf16_to_f32(v7.x);
    a1 += bf16_to_f32(v0.y) + bf16_to_f32(v1.y) + bf16_to_f32(v2.y) +
          bf16_to_f32(v3.y) + bf16_to_f32(v4.y) + bf16_to_f32(v5.y) +
          bf16_to_f32(v6.y) + bf16_to_f32(v7.y);
}

// Two rows gathered concurrently: 2 idx vectors + 16 row loads in flight.
__device__ __forceinline__ void gather2(const unsigned short* __restrict__ h,
                                        const unsigned short* __restrict__ csr,
                                        int i0, int e0, int i1, int e1, int fi,
                                        float& a00, float& a01, float& a10,
                                        float& a11) {
    while (i0 < e0 && i1 < e1) {
        ushort8v ia = *(const ushort8v*)(csr + i0);
        ushort8v ib = *(const ushort8v*)(csr + i1);
        ushort2 u0 = *(const ushort2*)(h + (size_t)ia[0] * HID + fi);
        ushort2 u1 = *(const ushort2*)(h + (size_t)ia[1] * HID + fi);
        ushort2 u2 = *(const ushort2*)(h + (size_t)ia[2] * HID + fi);
        ushort2 u3 = *(const ushort2*)(h + (size_t)ia[3] * HID + fi);
        ushort2 u4 = *(const ushort2*)(h + (size_t)ia[4] * HID + fi);
        ushort2 u5 = *(const ushort2*)(h + (size_t)ia[5] * HID + fi);
        ushort2 u6 = *(const ushort2*)(h + (size_t)ia[6] * HID + fi);
        ushort2 u7 = *(const ushort2*)(h + (size_t)ia[7] * HID + fi);
        ushort2 w0 = *(const ushort2*)(h + (size_t)ib[0] * HID + fi);
        ushort2 w1 = *(const ushort2*)(h + (size_t)ib[1] * HID + fi);
        ushort2 w2 = *(const ushort2*)(h + (size_t)ib[2] * HID + fi);
        ushort2 w3 = *(const ushort2*)(h + (size_t)ib[3] * HID + fi);
        ushort2 w4 = *(const ushort2*)(h + (size_t)ib[4] * HID + fi);
        ushort2 w5 = *(const ushort2*)(h + (size_t)ib[5] * HID + fi);
        ushort2 w6 = *(const ushort2*)(h + (size_t)ib[6] * HID + fi);
        ushort2 w7 = *(const ushort2*)(h + (size_t)ib[7] * HID + fi);
        a00 += bf16_to_f32(u0.x) + bf16_to_f32(u1.x) + bf16_to_f32(u2.x) +
               bf16_to_f32(u3.x) + bf16_to_f32(u4.x) + bf16_to_f32(u5.x) +
               bf16_to_f32(u6.x) + bf16_to_f32(u7.x);
        a01 += bf16_to_f32(u0.y) + bf16_to_f32(u1.y) + bf16_to_f32(u2.y) +
               bf16_to_f32(u3.y) + bf16_to_f32(u4.y) + bf16_to_f32(u5.y) +
               bf16_to_f32(u6.y) + bf16_to_f32(u7.y);
        a10 += bf16_to_f32(w0.x) + bf16_to_f32(w1.x) + bf16_to_f32(w2.x) +
               bf16_to_f32(w3.x) + bf16_to_f32(w4.x) + bf16_to_f32(w5.x) +
               bf16_to_f32(w6.x) + bf16_to_f32(w7.x);
        a11 += bf16_to_f32(w0.y) + bf16_to_f32(w1.y) + bf16_to_f32(w2.y) +
               bf16_to_f32(w3.y) + bf16_to_f32(w4.y) + bf16_to_f32(w5.y) +
               bf16_to_f32(w6.y) + bf16_to_f32(w7.y);
        i0 += 8;
        i1 += 8;
    }
    for (; i0 < e0; i0 += 8) gather_batch(h, csr, i0, fi, a00, a01);
    for (; i1 < e1; i1 += 8) gather_batch(h, csr, i1, fi, a10, a11);
}

// ---------------------------------------------------------------- degree ----
__global__ void deg_kernel(const int* __restrict__ dst, int* __restrict__ deg,
                           int n_edges) {
    int t = blockIdx.x * blockDim.x + threadIdx.x;
    int e0 = t * 4;
    if (e0 + 4 <= n_edges) {
        int4 d4 = *(const int4*)(dst + e0);
        atomicAdd(&deg[d4.x], 1);
        atomicAdd(&deg[d4.y], 1);
        atomicAdd(&deg[d4.z], 1);
        atomicAdd(&deg[d4.w], 1);
    } else {
        for (int e = e0; e < n_edges; e++) atomicAdd(&deg[dst[e]], 1);
    }
}

// ------------------------------------------- scan (padded to 8) + dinv ------
__global__ __launch_bounds__(256) void scan_phaseA(const int* __restrict__ deg,
                                                   float* __restrict__ dinv,
                                                   int* __restrict__ blocksum,
                                                   int N) {
    int i = blockIdx.x * 256 + threadIdx.x;
    int d = (i < N) ? deg[i] : 0;
    if (i < N) dinv[i] = rsqrtf((float)d + 1.0f);
    int v = (d + 7) & ~7;  // padded degree
#pragma unroll
    for (int off = 32; off > 0; off >>= 1) v += __shfl_down(v, off, 64);
    __shared__ int s[4];
    if ((threadIdx.x & 63) == 0) s[threadIdx.x >> 6] = v;
    __syncthreads();
    if (threadIdx.x == 0) blocksum[blockIdx.x] = s[0] + s[1] + s[2] + s[3];
}

__global__ __launch_bounds__(256) void scan_phaseB(int* __restrict__ blocksum,
                                                   int* __restrict__ blockoff,
                                                   int nblocks) {
    __shared__ int s[256];
    int t = threadIdx.x;
    int own = (t < nblocks) ? blocksum[t] : 0;
    s[t] = own;
    __syncthreads();
#pragma unroll
    for (int off = 1; off < 256; off <<= 1) {
        int v = (t >= off) ? s[t - off] : 0;
        __syncthreads();
        s[t] += v;
        __syncthreads();
    }
    if (t < nblocks) blockoff[t] = s[t] - own;  // exclusive
}

__global__ __launch_bounds__(256) void scan_phaseC(const int* __restrict__ deg,
                                                   const int* __restrict__ blockoff,
                                                   int* __restrict__ rowptr,
                                                   int* __restrict__ cursor, int N) {
    __shared__ int s[256];
    int t = threadIdx.x;
    int i = blockIdx.x * 256 + t;
    int own = (i < N) ? (deg[i] + 7) & ~7 : 0;
    s[t] = own;
    __syncthreads();
#pragma unroll
    for (int off = 1; off < 256; off <<= 1) {
        int v = (t >= off) ? s[t - off] : 0;
        __syncthreads();
        s[t] += v;
        __syncthreads();
    }
    if (i < N) {
        int r = blockoff[blockIdx.x] + s[t] - own;
        rowptr[i] = r;
        cursor[i] = r;               // seed: atomics return absolute positions
        if (i == N - 1) rowptr[N] = r + own;
    }
}

// ------------------------------------------------------------------ fill ----
__global__ void csr_fill(const int* __restrict__ src, const int* __restrict__ dst,
                         int* __restrict__ cursor,
                         unsigned short* __restrict__ csr_src, int n_edges) {
    int t = blockIdx.x * blockDim.x + threadIdx.x;
    int e0 = t * 4;
    if (e0 + 4 <= n_edges) {
        int4 d4 = *(const int4*)(dst + e0);
        int4 s4 = *(const int4*)(src + e0);
        int p0 = atomicAdd(&cursor[d4.x], 1);
        int p1 = atomicAdd(&cursor[d4.y], 1);
        int p2 = atomicAdd(&cursor[d4.z], 1);
        int p3 = atomicAdd(&cursor[d4.w], 1);
        csr_src[p0] = (unsigned short)s4.x;
        csr_src[p1] = (unsigned short)s4.y;
        csr_src[p2] = (unsigned short)s4.z;
        csr_src[p3] = (unsigned short)s4.w;
    } else {
        for (int e = e0; e < n_edges; e++) {
            int p = atomicAdd(&cursor[dst[e]], 1);
            csr_src[p] = (unsigned short)src[e];
        }
    }
}

// ----------------------------------------------------------- weight prep ----
__global__ void swizzle_W(const float* __restrict__ W0, const float* __restrict__ W1,
                          const float* __restrict__ W2, unsigned short* __restrict__ Wz) {
    const float* W = (blockIdx.x == 0) ? W0 : (blockIdx.x == 1) ? W1 : W2;
    unsigned short* dst = Wz + blockIdx.x * HID * HID;
    for (int e = threadIdx.x; e < HID * HID; e += blockDim.x) {
        int k = e / HID, n = e % HID;
        int nt = n >> 4, kki = k >> 5, quad = (k >> 3) & 3, j = k & 7;
        int lane = (n & 15) | (quad << 4);
        dst[(((nt * 3 + kki) * 64 + lane) << 3) | j] = f32_to_bf16(W[e]);
    }
}

__global__ void zero_sentinel(unsigned short* __restrict__ a,
                              unsigned short* __restrict__ b) {
    int t = threadIdx.x;  // 96 threads
    a[(size_t)SENT * HID + t] = 0;
    b[(size_t)SENT * HID + t] = 0;
}

// ----------------------------------------------------- GEMM0 (f32 input) ----
__global__ __launch_bounds__(256) void gemm0_f32(
    const float* __restrict__ X, const unsigned short* __restrict__ Wz,
    const float* __restrict__ dinv, unsigned short* __restrict__ Out, int Mtiles) {
    int wv = threadIdx.x >> 6;
    int lane = threadIdx.x & 63;
    int quad = lane >> 4;
    int mrow = lane & 15;
    int tt = blockIdx.x * 2 + (wv >> 1);
    int half = wv & 1;
    if (tt >= Mtiles) return;

    short8 bfrag[9];
    const short8* Wz8 = (const short8*)Wz;
#pragma unroll
    for (int f = 0; f < 9; f++) bfrag[f] = Wz8[(half * 9 + f) * 64 + lane];

    int m0 = tt * 16;
    const float* arow = X + (size_t)(m0 + mrow) * HID + quad * 8;
    short8 a[3];
#pragma unroll
    for (int kb = 0; kb < 3; kb++) {
        float4 u = *(const float4*)(arow + kb * 32);
        float4 v = *(const float4*)(arow + kb * 32 + 4);
        short8 t;
        t[0] = (short)f32_to_bf16(u.x); t[1] = (short)f32_to_bf16(u.y);
        t[2] = (short)f32_to_bf16(u.z); t[3] = (short)f32_to_bf16(u.w);
        t[4] = (short)f32_to_bf16(v.x); t[5] = (short)f32_to_bf16(v.y);
        t[6] = (short)f32_to_bf16(v.z); t[7] = (short)f32_to_bf16(v.w);
        a[kb] = t;
    }
    float dscale[4];
#pragma unroll
    for (int r = 0; r < 4; r++) dscale[r] = dinv[m0 + quad * 4 + r];
    unsigned short* orow = Out + (size_t)m0 * HID;
#pragma unroll
    for (int ntl = 0; ntl < 3; ntl++) {
        int nt = half * 3 + ntl;
        floatx4 c = {0.0f, 0.0f, 0.0f, 0.0f};
        c = __builtin_amdgcn_mfma_f32_16x16x32_bf16(a[0], bfrag[ntl * 3 + 0], c, 0, 0, 0);
        c = __builtin_amdgcn_mfma_f32_16x16x32_bf16(a[1], bfrag[ntl * 3 + 1], c, 0, 0, 0);
        c = __builtin_amdgcn_mfma_f32_16x16x32_bf16(a[2], bfrag[ntl * 3 + 2], c, 0, 0, 0);
#pragma unroll
        for (int r = 0; r < 4; r++)
            orow[(size_t)(quad * 4 + r) * HID + nt * 16 + mrow] =
                f32_to_bf16(c[r] * dscale[r]);
    }
}

// ------------------------------------------------ fused gather + GEMM -------
// 2 waves per 16-row tile; each gathers 8 rows (as 4 concurrent pairs) into
// the shared LDS tile, barrier, then MFMAs vs 3 of the 6 n-tiles.
__global__ __launch_bounds__(256) void fused_gather_gemm(
    const unsigned short* __restrict__ h, const int* __restrict__ rowptr,
    const unsigned short* __restrict__ csr, const float* __restrict__ dinv,
    const float* __restrict__ bias, const unsigned short* __restrict__ Wz,
    unsigned short* __restrict__ Out, int Mtiles) {
    __shared__ unsigned short tile[2][16][104];  // stride 104
    int wv = threadIdx.x >> 6;
    int lane = threadIdx.x & 63;
    int quad = lane >> 4;
    int mrow = lane & 15;
    int tsel = wv >> 1;
    int half = wv & 1;
    int tt = blockIdx.x * 2 + tsel;
    bool active = tt < Mtiles;
    int fi = (lane < 48) ? lane * 2 : 94;

    if (active) {
        float b0 = bias[fi], b1 = bias[fi + 1];
        int n0 = tt * 16;
        for (int jj = 0; jj < 8; jj += 2) {
            int j0 = half * 8 + jj;
            int na = n0 + j0;
            int nb = na + 1;
            int ia = rowptr[na];
            int ea = rowptr[na + 1];
            int ib = ea;               // rows contiguous: rowptr[nb] == rowptr[na+1]
            int eb = rowptr[nb + 1];
            float da = dinv[na], db = dinv[nb];
            ushort2 ha = *(const ushort2*)(h + (size_t)na * HID + fi);
            ushort2 hb = *(const ushort2*)(h + (size_t)nb * HID + fi);
            float a00 = bf16_to_f32(ha.x), a01 = bf16_to_f32(ha.y);
            float a10 = bf16_to_f32(hb.x), a11 = bf16_to_f32(hb.y);
            gather2(h, csr, ia, ea, ib, eb, fi, a00, a01, a10, a11);
            a00 = fmaxf(a00 * da + b0, 0.0f);
            a01 = fmaxf(a01 * da + b1, 0.0f);
            a10 = fmaxf(a10 * db + b0, 0.0f);
            a11 = fmaxf(a11 * db + b1, 0.0f);
            if (lane < 48) {
                tile[tsel][j0][fi] = f32_to_bf16(a00);
                tile[tsel][j0][fi + 1] = f32_to_bf16(a01);
                tile[tsel][j0 + 1][fi] = f32_to_bf16(a10);
                tile[tsel][j0 + 1][fi + 1] = f32_to_bf16(a11);
            }
        }
    }
    __syncthreads();
    if (!active) return;

    short8 bfrag[9];
    const short8* Wz8 = (const short8*)Wz;
#pragma unroll
    for (int f = 0; f < 9; f++) bfrag[f] = Wz8[(half * 9 + f) * 64 + lane];

    const unsigned short* tp = &tile[tsel][0][0];
    short8 a[3];
#pragma unroll
    for (int kb = 0; kb < 3; kb++)
        a[kb] = *(const short8*)(tp + mrow * 104 + quad * 8 + kb * 32);
    int n0 = tt * 16;
    float dscale[4];
#pragma unroll
    for (int r = 0; r < 4; r++) dscale[r] = dinv[n0 + quad * 4 + r];
    unsigned short* orow = Out + (size_t)n0 * HID;
#pragma unroll
    for (int ntl = 0; ntl < 3; ntl++) {
        int nt = half * 3 + ntl;
        floatx4 c = {0.0f, 0.0f, 0.0f, 0.0f};
        c = __builtin_amdgcn_mfma_f32_16x16x32_bf16(a[0], bfrag[ntl * 3 + 0], c, 0, 0, 0);
        c = __builtin_amdgcn_mfma_f32_16x16x32_bf16(a[1], bfrag[ntl * 3 + 1], c, 0, 0, 0);
        c = __builtin_amdgcn_mfma_f32_16x16x32_bf16(a[2], bfrag[ntl * 3 + 2], c, 0, 0, 0);
#pragma unroll
        for (int r = 0; r < 4; r++)
            orow[(size_t)(quad * 4 + r) * HID + nt * 16 + mrow] =
                f32_to_bf16(c[r] * dscale[r]);
    }
}

// ------------------------------------------------- fused gather + pool ------
// Wave per 8 nodes, gathered as 4 concurrent pairs; in-order run-length pool.
__global__ __launch_bounds__(256) void gather_pool(
    const unsigned short* __restrict__ h, const int* __restrict__ rowptr,
    const unsigned short* __restrict__ csr, const float* __restrict__ dinv,
    const float* __restrict__ bias, const int* __restrict__ batch,
    float* __restrict__ psum, float* __restrict__ pcnt, int Ntiles8) {
    int wv = threadIdx.x >> 6;
    int lane = threadIdx.x & 63;
    int tt = blockIdx.x * 4 + wv;
    if (tt >= Ntiles8) return;
    int fi = (lane < 48) ? lane * 2 : 94;
    float b0 = bias[fi], b1 = bias[fi + 1];

    int n0 = tt * 8;
    int g_cur = batch[n0];
    float s0 = 0.0f, s1 = 0.0f;
    int cnt = 0;
    for (int jj = 0; jj < 8; jj += 2) {
        int na = n0 + jj;
        int nb = na + 1;
        int ia = rowptr[na];
        int ea = rowptr[na + 1];
        int ib = ea;
        int eb = rowptr[nb + 1];
        float da = dinv[na], db = dinv[nb];
        ushort2 ha = *(const ushort2*)(h + (size_t)na * HID + fi);
        ushort2 hb = *(const ushort2*)(h + (size_t)nb * HID + fi);
        float a00 = bf16_to_f32(ha.x), a01 = bf16_to_f32(ha.y);
        float a10 = bf16_to_f32(hb.x), a11 = bf16_to_f32(hb.y);
        gather2(h, csr, ia, ea, ib, eb, fi, a00, a01, a10, a11);
        a00 = a00 * da + b0;  // last layer: no ReLU
        a01 = a01 * da + b1;
        a10 = a10 * db + b0;
        a11 = a11 * db + b1;
        // in-order pooling update for na then nb
        int ga = batch[na];
        if (ga != g_cur) {
            if (lane < 48) {
                atomicAdd(&psum[g_cur * HID + fi], s0);
                atomicAdd(&psum[g_cur * HID + fi + 1], s1);
            }
            if (lane == 0) atomicAdd(&pcnt[g_cur], (float)cnt);
            s0 = 0.0f; s1 = 0.0f; cnt = 0;
            g_cur = ga;
        }
        s0 += a00; s1 += a01; cnt++;
        int gb = batch[nb];
        if (gb != g_cur) {
            if (lane < 48) {
                atomicAdd(&psum[g_cur * HID + fi], s0);
                atomicAdd(&psum[g_cur * HID + fi + 1], s1);
            }
            if (lane == 0) atomicAdd(&pcnt[g_cur], (float)cnt);
            s0 = 0.0f; s1 = 0.0f; cnt = 0;
            g_cur = gb;
        }
        s0 += a10; s1 += a11; cnt++;
    }
    if (lane < 48) {
        atomicAdd(&psum[g_cur * HID + fi], s0);
        atomicAdd(&psum[g_cur * HID + fi + 1], s1);
    }
    if (lane == 0) atomicAdd(&pcnt[g_cur], (float)cnt);
}

// ---------------------------------------------------------------- head ------
__global__ __launch_bounds__(640) void final_kernel(
    const float* __restrict__ sums, const float* __restrict__ cnts,
    const float* __restrict__ Wlin, const float* __restrict__ blin,
    float* __restrict__ out) {
    int t = threadIdx.x;
    if (t >= NGRAPHS * 10) return;
    int g = t / 10;
    int c = t % 10;
    float denom = fmaxf(cnts[g], 1.0f);
    float acc = blin[c];
#pragma unroll
    for (int f = 0; f < HID; f++)
        acc += (sums[g * HID + f] / denom) * Wlin[f * 10 + c];
    out[t] = acc;
}

// ---------------------------------------------------------------- launch ----
extern "C" void kernel_launch(void* const* d_in, const int* in_sizes, int n_in,
                              void* d_out, int out_size, void* d_ws,
                              size_t ws_size, hipStream_t stream) {
    const float* x = (const float*)d_in[0];
    const int* edge = (const int*)d_in[1];
    const int* batch = (const int*)d_in[2];
    const float* W[3] = {(const float*)d_in[3], (const float*)d_in[5],
                         (const float*)d_in[7]};
    const float* B[3] = {(const float*)d_in[4], (const float*)d_in[6],
                         (const float*)d_in[8]};
    const float* Wlin = (const float*)d_in[9];
    const float* blin = (const float*)d_in[10];
    float* out = (float*)d_out;

    int N = in_sizes[0] / HID;  // 50000
    int E = in_sizes[1] / 2;    // 800000
    const int* src = edge;
    const int* dst = edge + E;
    int NB = (N + 255) / 256;

    char* ws = (char*)d_ws;
    size_t off = 0;
    auto alloc = [&](size_t bytes) {
        void* p = ws + off;
        off += (bytes + 255) & ~(size_t)255;
        return p;
    };
    int* deg = (int*)alloc((size_t)N * 4);
    float* dinv = (float*)alloc((size_t)N * 4);
    int* rowptr = (int*)alloc(((size_t)N + 1) * 4);
    int* cursor = (int*)alloc((size_t)N * 4);
    int* blocksum = (int*)alloc((size_t)NB * 4);
    int* blockoff = (int*)alloc((size_t)NB * 4);
    size_t csr_cap = (size_t)E + 8 * (size_t)N;
    unsigned short* csr_src = (unsigned short*)alloc(csr_cap * 2);
    unsigned short* Wz = (unsigned short*)alloc(3 * HID * HID * 2);
    unsigned short* bufA = (unsigned short*)alloc((size_t)NROWS * HID * 2);
    unsigned short* bufB = (unsigned short*)alloc((size_t)NROWS * HID * 2);
    float* psum = (float*)alloc((NGRAPHS * HID + NGRAPHS) * 4);
    float* pcnt = psum + NGRAPHS * HID;

    // --- CSR build + weight prep ---
    hipMemsetAsync(deg, 0, (size_t)N * 4, stream);
    hipMemsetAsync(csr_src, 0xC3, csr_cap * 2, stream);  // pads -> sentinel row
    hipMemsetAsync(psum, 0, (NGRAPHS * HID + NGRAPHS) * 4, stream);
    deg_kernel<<<(E / 4 + 255) / 256, 256, 0, stream>>>(dst, deg, E);
    scan_phaseA<<<NB, 256, 0, stream>>>(deg, dinv, blocksum, N);
    scan_phaseB<<<1, 256, 0, stream>>>(blocksum, blockoff, NB);
    scan_phaseC<<<NB, 256, 0, stream>>>(deg, blockoff, rowptr, cursor, N);
    csr_fill<<<(E / 4 + 255) / 256, 256, 0, stream>>>(src, dst, cursor, csr_src, E);
    swizzle_W<<<3, 256, 0, stream>>>(W[0], W[1], W[2], Wz);
    zero_sentinel<<<1, HID, 0, stream>>>(bufA, bufB);

    int Mtiles = (N + 15) / 16;           // 3125
    int grid2 = (Mtiles + 1) / 2;         // 1563 blocks (2 tiles/block)
    int Ntiles8 = (N + 7) / 8;            // 6250
    int gridp = (Ntiles8 + 3) / 4;        // 1563 blocks

    gemm0_f32<<<grid2, 256, 0, stream>>>(x, Wz, dinv, bufA, Mtiles);
    fused_gather_gemm<<<grid2, 256, 0, stream>>>(
        bufA, rowptr, csr_src, dinv, B[0], Wz + 1 * HID * HID, bufB, Mtiles);
    fused_gather_gemm<<<grid2, 256, 0, stream>>>(
        bufB, rowptr, csr_src, dinv, B[1], Wz + 2 * HID * HID, bufA, Mtiles);
    gather_pool<<<gridp, 256, 0, stream>>>(bufA, rowptr, csr_src, dinv, B[2],
                                           batch, psum, pcnt, Ntiles8);
    final_kernel<<<1, 640, 0, stream>>>(psum, pcnt, Wlin, blin, out);
}